// Round 1
// baseline (1210.488 us; speedup 1.0000x reference)
//
#include <hip/hip_runtime.h>
#include <stdint.h>

typedef short bf16x8 __attribute__((ext_vector_type(8)));
typedef float f32x4 __attribute__((ext_vector_type(4)));

#define NPOS 65536  // B*L = 64*1024
#define MB (1024ull * 1024ull)

__device__ __forceinline__ unsigned short f32_bf16(float f) {
    union { float f; unsigned u; } v; v.f = f;
    unsigned u = v.u;
    u += 0x7fffu + ((u >> 16) & 1u);
    return (unsigned short)(u >> 16);
}

// load 8 consecutive floats, round to bf16 fragment (scalar path)
__device__ __forceinline__ bf16x8 ldf8_bf16(const float* p) {
    const float4 lo = *(const float4*)p;
    const float4 hi = *(const float4*)(p + 4);
    bf16x8 v;
    v[0] = (short)f32_bf16(lo.x); v[1] = (short)f32_bf16(lo.y);
    v[2] = (short)f32_bf16(lo.z); v[3] = (short)f32_bf16(lo.w);
    v[4] = (short)f32_bf16(hi.x); v[5] = (short)f32_bf16(hi.y);
    v[6] = (short)f32_bf16(hi.z); v[7] = (short)f32_bf16(hi.w);
    return v;
}

// fast path: 8 floats -> bf16x8 via v_cvt_pk_bf16_f32 (RNE, same rounding)
__device__ __forceinline__ bf16x8 ldf8_bf16_pk(const float* p) {
    const float4 lo = *(const float4*)p;
    const float4 hi = *(const float4*)(p + 4);
    union { unsigned u[4]; bf16x8 v; } r;
    asm("v_cvt_pk_bf16_f32 %0, %1, %2" : "=v"(r.u[0]) : "v"(lo.x), "v"(lo.y));
    asm("v_cvt_pk_bf16_f32 %0, %1, %2" : "=v"(r.u[1]) : "v"(lo.z), "v"(lo.w));
    asm("v_cvt_pk_bf16_f32 %0, %1, %2" : "=v"(r.u[2]) : "v"(hi.x), "v"(hi.y));
    asm("v_cvt_pk_bf16_f32 %0, %1, %2" : "=v"(r.u[3]) : "v"(hi.z), "v"(hi.w));
    return r.v;
}

// fallback: encode ws_size (MiB) into output so a failing run tells us the budget
__global__ void ws_probe_k(float* __restrict__ out, float mib) {
    int i = blockIdx.x * 256 + threadIdx.x;
    if (i < 16384) out[i] = mib;
}

// ---- repack filter+gate weights (fp32 in) -> bf16 [layer][tap][oc 0..63 (f|g)][ic 0..31]
__global__ void repack_fgw_k(const float* __restrict__ fw,
                             const float* __restrict__ gw,
                             unsigned short* __restrict__ out) {
    int idx = blockIdx.x * 256 + threadIdx.x;  // < 40*3*64*32 = 245760
    int ic = idx & 31;
    int r1 = idx >> 5;
    int oc = r1 & 63;
    int r2 = r1 >> 6;      // i*3 + k
    int k  = r2 % 3;
    int i  = r2 / 3;
    const float* src = (oc < 32) ? fw : gw;
    out[idx] = f32_bf16(src[(((i * 32 + (oc & 31)) * 32 + ic) * 3) + k]);
}

// ---- start conv: x0[p][c] fp32, p = b*1024 + t
__global__ void start_conv_k(const float* __restrict__ in,
                             const float* __restrict__ sw,
                             float* __restrict__ x0) {
    int tid = threadIdx.x;
    int p = blockIdx.x * 64 + (tid >> 2);
    int c0 = (tid & 3) * 8;
    int b = p >> 10, t = p & 1023;
    float i0 = in[(b * 2 + 0) * 1024 + t];
    float i1 = in[(b * 2 + 1) * 1024 + t];
    float o[8];
#pragma unroll
    for (int j = 0; j < 8; ++j) {
        int c = c0 + j;
        o[j] = sw[c * 2 + 0] * i0 + sw[c * 2 + 1] * i1;
    }
    float4* dst = (float4*)(x0 + (size_t)p * 32 + c0);
    dst[0] = make_float4(o[0], o[1], o[2], o[3]);
    dst[1] = make_float4(o[4], o[5], o[6], o[7]);
}

// ---- one WaveNet layer in natural coords
__global__ __launch_bounds__(256) void layer_k(
    const float* __restrict__ xin, float* __restrict__ xout,
    const unsigned short* __restrict__ fgw,  // [3][64][32] bf16, this layer
    const float* __restrict__ rw,            // [32][32] fp32, this layer
    unsigned short* __restrict__ xg,         // [65536][32] bf16 out, this layer
    int d)
{
    __shared__ __align__(16) unsigned short lds1[64 * 40]; // xg tile [pos][ch pad40]
    __shared__ __align__(16) float lds2[64 * 36];          // res tile [pos][ch pad36]
    int tid = threadIdx.x;
    int w = tid >> 6, lane = tid & 63;
    int quad = lane >> 4, l15 = lane & 15;
    int p0 = blockIdx.x * 64;
    int b = p0 >> 10, t0 = p0 & 1023;
    int posl = w * 16 + l15;   // 0..63, wave covers 16 positions
    int tpos = t0 + posl;
    int ch0 = quad * 8;

    f32x4 zero = {0.f, 0.f, 0.f, 0.f};

    // B fragments, 3 taps: B[k=ch][n=pos], ch contiguous per lane
    bf16x8 bfr[3];
#pragma unroll
    for (int k = 0; k < 3; ++k) {
        int ts = tpos + (k - 1) * d;
        bf16x8 v;
#pragma unroll
        for (int j = 0; j < 8; ++j) v[j] = 0;
        if (ts >= 0 && ts < 1024)
            v = ldf8_bf16(xin + ((size_t)(b * 1024 + ts)) * 32 + ch0);
        bfr[k] = v;
    }

    f32x4 accf[2] = {zero, zero};
    f32x4 accg[2] = {zero, zero};
#pragma unroll
    for (int k = 0; k < 3; ++k) {
        const unsigned short* wb = fgw + (size_t)k * 64 * 32;
#pragma unroll
        for (int mt = 0; mt < 2; ++mt) {
            bf16x8 af = *(const bf16x8*)(wb + (mt * 16 + l15) * 32 + ch0);
            accf[mt] = __builtin_amdgcn_mfma_f32_16x16x32_bf16(af, bfr[k], accf[mt], 0, 0, 0);
        }
#pragma unroll
        for (int mt = 0; mt < 2; ++mt) {
            bf16x8 ag = *(const bf16x8*)(wb + ((mt + 2) * 16 + l15) * 32 + ch0);
            accg[mt] = __builtin_amdgcn_mfma_f32_16x16x32_bf16(ag, bfr[k], accg[mt], 0, 0, 0);
        }
    }

    // gated activation -> bf16 xg into LDS (C/D layout: row=quad*4+r, col=l15)
#pragma unroll
    for (int mt = 0; mt < 2; ++mt)
#pragma unroll
        for (int r = 0; r < 4; ++r) {
            float fv = accf[mt][r], gv = accg[mt][r];
            float th = 1.0f - 2.0f / (1.0f + __expf(2.0f * fv));
            float sg = 1.0f / (1.0f + __expf(-gv));
            lds1[posl * 40 + mt * 16 + quad * 4 + r] = f32_bf16(th * sg);
        }
    __syncthreads();

    // coalesced xg store
    {
        int pp = tid >> 2, c0s = (tid & 3) * 8;
        int4 v = *(const int4*)(lds1 + pp * 40 + c0s);
        *(int4*)(xg + ((size_t)(p0 + pp)) * 32 + c0s) = v;
    }

    // res 1x1 GEMM from LDS xg
    bf16x8 bx = *(const bf16x8*)(lds1 + posl * 40 + ch0);
    f32x4 accr[2] = {zero, zero};
#pragma unroll
    for (int rt = 0; rt < 2; ++rt) {
        bf16x8 ar = ldf8_bf16(rw + (rt * 16 + l15) * 32 + ch0);
        accr[rt] = __builtin_amdgcn_mfma_f32_16x16x32_bf16(ar, bx, accr[rt], 0, 0, 0);
    }
#pragma unroll
    for (int rt = 0; rt < 2; ++rt)
#pragma unroll
        for (int r = 0; r < 4; ++r)
            lds2[posl * 36 + rt * 16 + quad * 4 + r] = accr[rt][r];
    __syncthreads();

    // x_new = res + x_old (fp32, coalesced)
    {
        int pp = tid >> 2, c0s = (tid & 3) * 8;
        const float* xi = xin + ((size_t)(p0 + pp)) * 32 + c0s;
        float* xo = xout + ((size_t)(p0 + pp)) * 32 + c0s;
        float4 a0 = *(const float4*)(xi);
        float4 a1 = *(const float4*)(xi + 4);
        float4 d0 = *(const float4*)(lds2 + pp * 36 + c0s);
        float4 d1 = *(const float4*)(lds2 + pp * 36 + c0s + 4);
        *(float4*)(xo)     = make_float4(a0.x + d0.x, a0.y + d0.y, a0.z + d0.z, a0.w + d0.w);
        *(float4*)(xo + 4) = make_float4(a1.x + d1.x, a1.y + d1.y, a1.z + d1.z, a1.w + d1.w);
    }
}

// ---- skip GEMM over all layers: relu(sum_i skip_w[i] @ xg[i]) -> [sc][b*1024+t] bf16
// v2: 32-pos tiles (grid 2048), 1-deep B prefetch, cvt_pk weight conversion.
//     acc 32 VGPR + 20KB LDS -> ~6-8 blocks/CU for latency hiding.
__global__ __launch_bounds__(256) void skip_gemm_k(
    const unsigned short* __restrict__ xg_all,  // [40][65536][32] bf16
    const float* __restrict__ sw,               // [40][256][32] fp32
    unsigned short* __restrict__ sk)            // [256][65536] bf16
{
    __shared__ __align__(16) unsigned short lds[256 * 40];  // [sc][pos pad40]
    int tid = threadIdx.x;
    int w = tid >> 6, lane = tid & 63;
    int quad = lane >> 4, l15 = lane & 15;
    int p0 = blockIdx.x * 32;
    f32x4 zero = {0.f, 0.f, 0.f, 0.f};
    f32x4 acc[4][2];
#pragma unroll
    for (int a = 0; a < 4; ++a)
#pragma unroll
        for (int c = 0; c < 2; ++c) acc[a][c] = zero;

    // B fragment addressing: pos = p0 + ct*16 + l15, ch = quad*8..+7
    bf16x8 bcur[2], bnxt[2];
#pragma unroll
    for (int ct = 0; ct < 2; ++ct)
        bcur[ct] = *(const bf16x8*)(xg_all + ((size_t)(p0 + ct * 16 + l15)) * 32 + quad * 8);

    // body: A-frags (cvt_pk) + 8 MFMA against bcur
    auto compute = [&](int i) {
        const float* wsrc = sw + ((size_t)i * 256 + w * 64) * 32;
#pragma unroll
        for (int rt = 0; rt < 4; ++rt) {
            bf16x8 a = ldf8_bf16_pk(wsrc + (rt * 16 + l15) * 32 + quad * 8);
#pragma unroll
            for (int ct = 0; ct < 2; ++ct)
                acc[rt][ct] = __builtin_amdgcn_mfma_f32_16x16x32_bf16(a, bcur[ct], acc[rt][ct], 0, 0, 0);
        }
    };

    for (int i = 0; i < 39; ++i) {
        // prefetch next layer's B while MFMAing current
        const unsigned short* src = xg_all + ((size_t)(i + 1) * NPOS + p0) * 32;
#pragma unroll
        for (int ct = 0; ct < 2; ++ct)
            bnxt[ct] = *(const bf16x8*)(src + (ct * 16 + l15) * 32 + quad * 8);
        compute(i);
        bcur[0] = bnxt[0]; bcur[1] = bnxt[1];
    }
    compute(39);

    // relu + bf16, transpose-stage through LDS
#pragma unroll
    for (int rt = 0; rt < 4; ++rt)
#pragma unroll
        for (int ct = 0; ct < 2; ++ct)
#pragma unroll
            for (int r = 0; r < 4; ++r) {
                float v = acc[rt][ct][r];
                v = v > 0.f ? v : 0.f;
                lds[(w * 64 + rt * 16 + quad * 4 + r) * 40 + ct * 16 + l15] = f32_bf16(v);
            }
    __syncthreads();
    // store: 256 sc rows x 32 pos = 1024 16B chunks; 4 lanes cover one 64B row
#pragma unroll
    for (int j = 0; j < 4; ++j) {
        int idx = tid + 256 * j;
        int sc = idx >> 2, tc = idx & 3;
        int4 v = *(const int4*)(lds + sc * 40 + tc * 8);
        *(int4*)(sk + (size_t)sc * NPOS + p0 + tc * 8) = v;
    }
}

// ---- FC split-K partials: block kb handles (sc = kb>>1, t-half = (kb&1)*512)
__global__ __launch_bounds__(256) void fc_part_k(
    const unsigned short* __restrict__ sk,    // [256][65536] bf16 = [sc][b*1024+t]
    const float* __restrict__ fw,             // [256][262144] fp32, k = sc*1024+t
    float* __restrict__ part)                 // [512][64][256]
{
    int tid = threadIdx.x;
    int w = tid >> 6, lane = tid & 63;
    int quad = lane >> 4, l15 = lane & 15;
    int kb = blockIdx.x;
    int sc = kb >> 1;
    int tbase = (kb & 1) * 512;
    f32x4 zero = {0.f, 0.f, 0.f, 0.f};
    f32x4 acc[4][4];
#pragma unroll
    for (int a = 0; a < 4; ++a)
#pragma unroll
        for (int c = 0; c < 4; ++c) acc[a][c] = zero;

    for (int it = 0; it < 16; ++it) {
        int tk = tbase + it * 32 + quad * 8;
        bf16x8 af[4];
#pragma unroll
        for (int rt = 0; rt < 4; ++rt)
            af[rt] = *(const bf16x8*)(sk + (size_t)sc * NPOS + (rt * 16 + l15) * 1024 + tk);
#pragma unroll
        for (int ct = 0; ct < 4; ++ct) {
            bf16x8 bw = ldf8_bf16(fw + (size_t)(w * 64 + ct * 16 + l15) * 262144 + sc * 1024 + tk);
#pragma unroll
            for (int rt = 0; rt < 4; ++rt)
                acc[rt][ct] = __builtin_amdgcn_mfma_f32_16x16x32_bf16(af[rt], bw, acc[rt][ct], 0, 0, 0);
        }
    }
#pragma unroll
    for (int rt = 0; rt < 4; ++rt)
#pragma unroll
        for (int ct = 0; ct < 4; ++ct)
#pragma unroll
            for (int r = 0; r < 4; ++r) {
                int bb = rt * 16 + quad * 4 + r;
                int cls = w * 64 + ct * 16 + l15;
                part[((size_t)kb * 64 + bb) * 256 + cls] = acc[rt][ct][r];
            }
}

__global__ void fc_reduce_k(const float* __restrict__ part,
                            const float* __restrict__ fb,
                            float* __restrict__ out) {
    int b = blockIdx.x, cls = threadIdx.x;
    float s = fb[cls];
    for (int kb = 0; kb < 512; ++kb)
        s += part[((size_t)kb * 64 + b) * 256 + cls];
    out[b * 256 + cls] = s;   // fp32 output
}

extern "C" void kernel_launch(void* const* d_in, const int* in_sizes, int n_in,
                              void* d_out, int out_size, void* d_ws, size_t ws_size,
                              hipStream_t stream) {
    const float* input    = (const float*)d_in[0];
    const float* start_w  = (const float*)d_in[1];
    const float* filter_w = (const float*)d_in[2];
    const float* gate_w   = (const float*)d_in[3];
    const float* res_w    = (const float*)d_in[4];
    const float* skip_w   = (const float*)d_in[5];
    const float* fc_w     = (const float*)d_in[6];
    const float* fc_b     = (const float*)d_in[7];
    float* out = (float*)d_out;

    // Overlay layout (phases A: layers, B: skip gemm, C: fc):
    //   [0, 160MB)      xg_all (A,B)   | part (C, 32MB)
    //   [160MB, 192MB)  skipb (B,C)    | xa 8MB + xb 8MB + fgw 0.5MB (A)
    const size_t REQUIRED = 192 * MB;
    if (ws_size < REQUIRED) {
        ws_probe_k<<<64, 256, 0, stream>>>(out, (float)(ws_size >> 20));
        return;
    }

    char* ws = (char*)d_ws;
    unsigned short* xg_all = (unsigned short*)(ws);             // 160MB
    float*          part   = (float*)(ws);                      // 32MB (phase C)
    unsigned short* skipb  = (unsigned short*)(ws + 160 * MB);  // 32MB
    float*          xa     = (float*)(ws + 160 * MB);           // 8MB (phase A)
    float*          xb     = (float*)(ws + 168 * MB);           // 8MB (phase A)
    unsigned short* fgw    = (unsigned short*)(ws + 176 * MB);  // 480KB (phase A)

    repack_fgw_k<<<960, 256, 0, stream>>>(filter_w, gate_w, fgw);
    start_conv_k<<<1024, 256, 0, stream>>>(input, start_w, xa);

    float* xi = xa;
    float* xo = xb;
    for (int i = 0; i < 40; ++i) {
        int d = 1 << (i % 10);
        layer_k<<<1024, 256, 0, stream>>>(xi, xo,
                                          fgw + (size_t)i * 3 * 64 * 32,
                                          res_w + (size_t)i * 32 * 32,
                                          xg_all + (size_t)i * NPOS * 32, d);
        float* tmp = xi; xi = xo; xo = tmp;
    }

    skip_gemm_k<<<2048, 256, 0, stream>>>(xg_all, skip_w, skipb);
    fc_part_k<<<512, 256, 0, stream>>>(skipb, fc_w, part);
    fc_reduce_k<<<64, 256, 0, stream>>>(part, fc_b, out);
}

// Round 3
// 984.929 us; speedup vs baseline: 1.2290x; 1.2290x over previous
//
#include <hip/hip_runtime.h>
#include <stdint.h>

typedef short bf16x8 __attribute__((ext_vector_type(8)));
typedef float f32x4 __attribute__((ext_vector_type(4)));

#define NPOS 65536  // B*L = 64*1024
#define MB (1024ull * 1024ull)
#define SK_PIECE 2097152  // shorts per 4MB piece of the in-place skip output

__device__ __forceinline__ unsigned short f32_bf16(float f) {
    union { float f; unsigned u; } v; v.f = f;
    unsigned u = v.u;
    u += 0x7fffu + ((u >> 16) & 1u);
    return (unsigned short)(u >> 16);
}

// load 8 consecutive floats, round to bf16 fragment (scalar path)
__device__ __forceinline__ bf16x8 ldf8_bf16(const float* p) {
    const float4 lo = *(const float4*)p;
    const float4 hi = *(const float4*)(p + 4);
    bf16x8 v;
    v[0] = (short)f32_bf16(lo.x); v[1] = (short)f32_bf16(lo.y);
    v[2] = (short)f32_bf16(lo.z); v[3] = (short)f32_bf16(lo.w);
    v[4] = (short)f32_bf16(hi.x); v[5] = (short)f32_bf16(hi.y);
    v[6] = (short)f32_bf16(hi.z); v[7] = (short)f32_bf16(hi.w);
    return v;
}

// fallback: encode ws_size (MiB) into output so a failing run tells us the budget
__global__ void ws_probe_k(float* __restrict__ out, float mib) {
    int i = blockIdx.x * 256 + threadIdx.x;
    if (i < 16384) out[i] = mib;
}

// ---- repack filter+gate weights (fp32 in) -> bf16 [layer][tap][oc 0..63 (f|g)][ic 0..31]
__global__ void repack_fgw_k(const float* __restrict__ fw,
                             const float* __restrict__ gw,
                             unsigned short* __restrict__ out) {
    int idx = blockIdx.x * 256 + threadIdx.x;  // < 40*3*64*32 = 245760
    int ic = idx & 31;
    int r1 = idx >> 5;
    int oc = r1 & 63;
    int r2 = r1 >> 6;      // i*3 + k
    int k  = r2 % 3;
    int i  = r2 / 3;
    const float* src = (oc < 32) ? fw : gw;
    out[idx] = f32_bf16(src[(((i * 32 + (oc & 31)) * 32 + ic) * 3) + k]);
}

// ---- repack skip weights fp32 -> bf16, same layout [40][256][32]
__global__ void repack_sw_k(const float* __restrict__ sw,
                            unsigned short* __restrict__ out) {
    int idx = blockIdx.x * 256 + threadIdx.x;  // < 40*256*32 = 327680
    out[idx] = f32_bf16(sw[idx]);
}

// ---- start conv: x0[p][c] fp32, p = b*1024 + t
__global__ void start_conv_k(const float* __restrict__ in,
                             const float* __restrict__ sw,
                             float* __restrict__ x0) {
    int tid = threadIdx.x;
    int p = blockIdx.x * 64 + (tid >> 2);
    int c0 = (tid & 3) * 8;
    int b = p >> 10, t = p & 1023;
    float i0 = in[(b * 2 + 0) * 1024 + t];
    float i1 = in[(b * 2 + 1) * 1024 + t];
    float o[8];
#pragma unroll
    for (int j = 0; j < 8; ++j) {
        int c = c0 + j;
        o[j] = sw[c * 2 + 0] * i0 + sw[c * 2 + 1] * i1;
    }
    float4* dst = (float4*)(x0 + (size_t)p * 32 + c0);
    dst[0] = make_float4(o[0], o[1], o[2], o[3]);
    dst[1] = make_float4(o[4], o[5], o[6], o[7]);
}

// ---- one WaveNet layer in natural coords
__global__ __launch_bounds__(256) void layer_k(
    const float* __restrict__ xin, float* __restrict__ xout,
    const unsigned short* __restrict__ fgw,  // [3][64][32] bf16, this layer
    const float* __restrict__ rw,            // [32][32] fp32, this layer
    unsigned short* __restrict__ xg,         // [65536][32] bf16 out, this layer
    int d)
{
    __shared__ __align__(16) unsigned short lds1[64 * 40]; // xg tile [pos][ch pad40]
    __shared__ __align__(16) float lds2[64 * 36];          // res tile [pos][ch pad36]
    int tid = threadIdx.x;
    int w = tid >> 6, lane = tid & 63;
    int quad = lane >> 4, l15 = lane & 15;
    int p0 = blockIdx.x * 64;
    int b = p0 >> 10, t0 = p0 & 1023;
    int posl = w * 16 + l15;   // 0..63, wave covers 16 positions
    int tpos = t0 + posl;
    int ch0 = quad * 8;

    f32x4 zero = {0.f, 0.f, 0.f, 0.f};

    // B fragments, 3 taps: B[k=ch][n=pos], ch contiguous per lane
    bf16x8 bfr[3];
#pragma unroll
    for (int k = 0; k < 3; ++k) {
        int ts = tpos + (k - 1) * d;
        bf16x8 v;
#pragma unroll
        for (int j = 0; j < 8; ++j) v[j] = 0;
        if (ts >= 0 && ts < 1024)
            v = ldf8_bf16(xin + ((size_t)(b * 1024 + ts)) * 32 + ch0);
        bfr[k] = v;
    }

    f32x4 accf[2] = {zero, zero};
    f32x4 accg[2] = {zero, zero};
#pragma unroll
    for (int k = 0; k < 3; ++k) {
        const unsigned short* wb = fgw + (size_t)k * 64 * 32;
#pragma unroll
        for (int mt = 0; mt < 2; ++mt) {
            bf16x8 af = *(const bf16x8*)(wb + (mt * 16 + l15) * 32 + ch0);
            accf[mt] = __builtin_amdgcn_mfma_f32_16x16x32_bf16(af, bfr[k], accf[mt], 0, 0, 0);
        }
#pragma unroll
        for (int mt = 0; mt < 2; ++mt) {
            bf16x8 ag = *(const bf16x8*)(wb + ((mt + 2) * 16 + l15) * 32 + ch0);
            accg[mt] = __builtin_amdgcn_mfma_f32_16x16x32_bf16(ag, bfr[k], accg[mt], 0, 0, 0);
        }
    }

    // gated activation -> bf16 xg into LDS (C/D layout: row=quad*4+r, col=l15)
#pragma unroll
    for (int mt = 0; mt < 2; ++mt)
#pragma unroll
        for (int r = 0; r < 4; ++r) {
            float fv = accf[mt][r], gv = accg[mt][r];
            float th = 1.0f - 2.0f / (1.0f + __expf(2.0f * fv));
            float sg = 1.0f / (1.0f + __expf(-gv));
            lds1[posl * 40 + mt * 16 + quad * 4 + r] = f32_bf16(th * sg);
        }
    __syncthreads();

    // coalesced xg store
    {
        int pp = tid >> 2, c0s = (tid & 3) * 8;
        int4 v = *(const int4*)(lds1 + pp * 40 + c0s);
        *(int4*)(xg + ((size_t)(p0 + pp)) * 32 + c0s) = v;
    }

    // res 1x1 GEMM from LDS xg
    bf16x8 bx = *(const bf16x8*)(lds1 + posl * 40 + ch0);
    f32x4 accr[2] = {zero, zero};
#pragma unroll
    for (int rt = 0; rt < 2; ++rt) {
        bf16x8 ar = ldf8_bf16(rw + (rt * 16 + l15) * 32 + ch0);
        accr[rt] = __builtin_amdgcn_mfma_f32_16x16x32_bf16(ar, bx, accr[rt], 0, 0, 0);
    }
#pragma unroll
    for (int rt = 0; rt < 2; ++rt)
#pragma unroll
        for (int r = 0; r < 4; ++r)
            lds2[posl * 36 + rt * 16 + quad * 4 + r] = accr[rt][r];
    __syncthreads();

    // x_new = res + x_old (fp32, coalesced)
    {
        int pp = tid >> 2, c0s = (tid & 3) * 8;
        const float* xi = xin + ((size_t)(p0 + pp)) * 32 + c0s;
        float* xo = xout + ((size_t)(p0 + pp)) * 32 + c0s;
        float4 a0 = *(const float4*)(xi);
        float4 a1 = *(const float4*)(xi + 4);
        float4 d0 = *(const float4*)(lds2 + pp * 36 + c0s);
        float4 d1 = *(const float4*)(lds2 + pp * 36 + c0s + 4);
        *(float4*)(xo)     = make_float4(a0.x + d0.x, a0.y + d0.y, a0.z + d0.z, a0.w + d0.w);
        *(float4*)(xo + 4) = make_float4(a1.x + d1.x, a1.y + d1.y, a1.z + d1.z, a1.w + d1.w);
    }
}

// ---- skip GEMM over all layers: relu(sum_i skip_w[i] @ xg[i]) -> in-place piece layout
// v4: 64-pos tile, pre-repacked bf16 weights, 1-layer-deep software pipeline on
//     A (L2-resident weights) and B (xg HBM/L3 stream). Steady-state body =
//     8x 16B loads + 16 MFMA.
// Output written IN PLACE over the xg layer-0..7 region (block pb's exclusive
// columns): piece j=sc>>5 at  j*4MB + pb*4KB + (sc&31)*128B + (pos&63)*2B.
__global__ __launch_bounds__(256) void skip_gemm_k(
    const unsigned short* __restrict__ xg_all,  // [40][65536][32] bf16
    const unsigned short* __restrict__ swb,     // [40][256][32] bf16
    unsigned short* __restrict__ sk)            // == xg_all base (in-place)
{
    __shared__ __align__(16) unsigned short lds[256 * 72];
    int tid = threadIdx.x;
    int w = tid >> 6, lane = tid & 63;
    int quad = lane >> 4, l15 = lane & 15;
    int p0 = blockIdx.x * 64;
    f32x4 zero = {0.f, 0.f, 0.f, 0.f};
    f32x4 acc[4][4];
#pragma unroll
    for (int a = 0; a < 4; ++a)
#pragma unroll
        for (int c = 0; c < 4; ++c) acc[a][c] = zero;

    // per-lane bases; layer stride for B = NPOS*32, for A = 256*32 = 8192
    const unsigned short* bbase = xg_all + ((size_t)(p0 + l15)) * 32 + quad * 8;
    const unsigned short* abase = swb + ((size_t)(w * 64 + l15)) * 32 + quad * 8;

    bf16x8 bcur[4], acur[4], bnxt[4], anxt[4];
#pragma unroll
    for (int ct = 0; ct < 4; ++ct) bcur[ct] = *(const bf16x8*)(bbase + ct * 512);
#pragma unroll
    for (int rt = 0; rt < 4; ++rt) acur[rt] = *(const bf16x8*)(abase + rt * 512);

#pragma unroll 2
    for (int i = 0; i < 40; ++i) {
        if (i < 39) {
            const unsigned short* bn = bbase + (size_t)(i + 1) * NPOS * 32;
            const unsigned short* an = abase + (size_t)(i + 1) * 8192;
#pragma unroll
            for (int ct = 0; ct < 4; ++ct) bnxt[ct] = *(const bf16x8*)(bn + ct * 512);
#pragma unroll
            for (int rt = 0; rt < 4; ++rt) anxt[rt] = *(const bf16x8*)(an + rt * 512);
        }
#pragma unroll
        for (int rt = 0; rt < 4; ++rt)
#pragma unroll
            for (int ct = 0; ct < 4; ++ct)
                acc[rt][ct] = __builtin_amdgcn_mfma_f32_16x16x32_bf16(acur[rt], bcur[ct], acc[rt][ct], 0, 0, 0);
#pragma unroll
        for (int ct = 0; ct < 4; ++ct) bcur[ct] = bnxt[ct];
#pragma unroll
        for (int rt = 0; rt < 4; ++rt) acur[rt] = anxt[rt];
    }

    // relu + bf16, transpose-stage through LDS
#pragma unroll
    for (int rt = 0; rt < 4; ++rt)
#pragma unroll
        for (int ct = 0; ct < 4; ++ct)
#pragma unroll
            for (int r = 0; r < 4; ++r) {
                float v = acc[rt][ct][r];
                v = v > 0.f ? v : 0.f;
                lds[(w * 64 + rt * 16 + quad * 4 + r) * 72 + ct * 16 + l15] = f32_bf16(v);
            }
    __syncthreads();
    // in-place piece store: all reads of this block's columns are done above
    {
        size_t pbbase = (size_t)(p0 >> 6) * 2048;
#pragma unroll
        for (int j = 0; j < 8; ++j) {
            int idx = tid + 256 * j;      // 2048 16B chunks
            int sc = idx >> 3, tc = idx & 7;
            int4 v = *(const int4*)(lds + sc * 72 + tc * 8);
            unsigned short* dst = sk + (size_t)(sc >> 5) * SK_PIECE + pbbase
                                     + (sc & 31) * 64 + tc * 8;
            *(int4*)dst = v;
        }
    }
}

// ---- FC split-K partials: block kb handles (sc = kb>>1, t-half = (kb&1)*512)
__global__ __launch_bounds__(256) void fc_part_k(
    const unsigned short* __restrict__ sk,    // in-place piece layout (see skip_gemm_k)
    const float* __restrict__ fw,             // [256][262144] fp32, k = sc*1024+t
    float* __restrict__ part)                 // [512][64][256]
{
    int tid = threadIdx.x;
    int w = tid >> 6, lane = tid & 63;
    int quad = lane >> 4, l15 = lane & 15;
    int kb = blockIdx.x;
    int sc = kb >> 1;
    int tbase = (kb & 1) * 512;
    f32x4 zero = {0.f, 0.f, 0.f, 0.f};
    f32x4 acc[4][4];
#pragma unroll
    for (int a = 0; a < 4; ++a)
#pragma unroll
        for (int c = 0; c < 4; ++c) acc[a][c] = zero;

    const unsigned short* skp = sk + (size_t)(sc >> 5) * SK_PIECE + (sc & 31) * 64;

    for (int it = 0; it < 16; ++it) {
        int t = tbase + it * 32 + quad * 8;
        bf16x8 af[4];
#pragma unroll
        for (int rt = 0; rt < 4; ++rt) {
            int b = rt * 16 + l15;
            af[rt] = *(const bf16x8*)(skp + (size_t)(b * 16 + (t >> 6)) * 2048 + (t & 63));
        }
#pragma unroll
        for (int ct = 0; ct < 4; ++ct) {
            bf16x8 bw = ldf8_bf16(fw + (size_t)(w * 64 + ct * 16 + l15) * 262144 + sc * 1024 + t);
#pragma unroll
            for (int rt = 0; rt < 4; ++rt)
                acc[rt][ct] = __builtin_amdgcn_mfma_f32_16x16x32_bf16(af[rt], bw, acc[rt][ct], 0, 0, 0);
        }
    }
#pragma unroll
    for (int rt = 0; rt < 4; ++rt)
#pragma unroll
        for (int ct = 0; ct < 4; ++ct)
#pragma unroll
            for (int r = 0; r < 4; ++r) {
                int bb = rt * 16 + quad * 4 + r;
                int cls = w * 64 + ct * 16 + l15;
                part[((size_t)kb * 64 + bb) * 256 + cls] = acc[rt][ct][r];
            }
}

__global__ void fc_reduce_k(const float* __restrict__ part,
                            const float* __restrict__ fb,
                            float* __restrict__ out) {
    int b = blockIdx.x, cls = threadIdx.x;
    float s = fb[cls];
    for (int kb = 0; kb < 512; ++kb)
        s += part[((size_t)kb * 64 + b) * 256 + cls];
    out[b * 256 + cls] = s;   // fp32 output
}

extern "C" void kernel_launch(void* const* d_in, const int* in_sizes, int n_in,
                              void* d_out, int out_size, void* d_ws, size_t ws_size,
                              hipStream_t stream) {
    const float* input    = (const float*)d_in[0];
    const float* start_w  = (const float*)d_in[1];
    const float* filter_w = (const float*)d_in[2];
    const float* gate_w   = (const float*)d_in[3];
    const float* res_w    = (const float*)d_in[4];
    const float* skip_w   = (const float*)d_in[5];
    const float* fc_w     = (const float*)d_in[6];
    const float* fc_b     = (const float*)d_in[7];
    float* out = (float*)d_out;

    // Overlay layout (phases A: layers, B: skip gemm, C: fc):
    //   [0, 160MB)        xg_all (A,B)   | sk = xg layers 0-7, in-place (B out, C in)
    //   [32MB, 64MB)      part (C)       | aliases xg layers 8-15, dead in C
    //   [160MB, 176MB)    xa 8MB + xb 8MB (A)
    //   [176MB, 176.5MB)  fgw (A)
    //   [176.5, 177.125)  swb (A write, B read) — no overlap with any B-phase writes
    const size_t REQUIRED = 192 * MB;
    if (ws_size < REQUIRED) {
        ws_probe_k<<<64, 256, 0, stream>>>(out, (float)(ws_size >> 20));
        return;
    }

    char* ws = (char*)d_ws;
    unsigned short* xg_all = (unsigned short*)(ws);             // 160MB
    unsigned short* sk     = (unsigned short*)(ws);             // 32MB in-place (B,C)
    float*          part   = (float*)(ws + 32 * MB);            // 32MB (phase C)
    float*          xa     = (float*)(ws + 160 * MB);           // 8MB (phase A)
    float*          xb     = (float*)(ws + 168 * MB);           // 8MB (phase A)
    unsigned short* fgw    = (unsigned short*)(ws + 176 * MB);  // 480KB (phase A)
    unsigned short* swb    = (unsigned short*)(ws + 176 * MB + 512 * 1024); // 640KB (A,B)

    repack_fgw_k<<<960, 256, 0, stream>>>(filter_w, gate_w, fgw);
    repack_sw_k<<<1280, 256, 0, stream>>>(skip_w, swb);
    start_conv_k<<<1024, 256, 0, stream>>>(input, start_w, xa);

    float* xi = xa;
    float* xo = xb;
    for (int i = 0; i < 40; ++i) {
        int d = 1 << (i % 10);
        layer_k<<<1024, 256, 0, stream>>>(xi, xo,
                                          fgw + (size_t)i * 3 * 64 * 32,
                                          res_w + (size_t)i * 32 * 32,
                                          xg_all + (size_t)i * NPOS * 32, d);
        float* tmp = xi; xi = xo; xo = tmp;
    }

    skip_gemm_k<<<1024, 256, 0, stream>>>(xg_all, swb, sk);
    fc_part_k<<<512, 256, 0, stream>>>(sk, fc_w, part);
    fc_reduce_k<<<64, 256, 0, stream>>>(part, fc_b, out);
}